// Round 5
// baseline (250.317 us; speedup 1.0000x reference)
//
#include <hip/hip_runtime.h>
#include <hip/hip_bf16.h>

// Problem geometry (fixed by setup_inputs)
#define BATCH 4
#define DZ 96
#define DY 192
#define DX 192
#define ZS (DY * DX)            // 36864
#define SVOL ((size_t)DZ * ZS)  // 3538944 voxels per batch item
#define NTOT ((double)(BATCH * (double)SVOL))
#define VOX_PER_THREAD 8
#define BLOCK 256
#define BLOCKS_PER_BATCH ((int)(SVOL / (VOX_PER_THREAD * BLOCK))) // 1728
#define GRID (BATCH * BLOCKS_PER_BATCH)                           // 6912

// Exact expanding-box search for voxels whose entire (in-bounds) 26-neighborhood
// matches their own class (expected ~0 such voxels on Bernoulli targets).
// Returns D = L-inf distance to nearest opposite-class voxel, capped at 21.
__device__ __noinline__ int far_dist(const int* __restrict__ T, size_t bOff,
                                     int z, int y, int x, int tv) {
    for (int r = 2; r <= 20; ++r) {
        int zlo = max(z - r, 0), zhi = min(z + r, DZ - 1);
        int ylo = max(y - r, 0), yhi = min(y + r, DY - 1);
        int xlo = max(x - r, 0), xhi = min(x + r, DX - 1);
        for (int zz = zlo; zz <= zhi; ++zz)
            for (int yy = ylo; yy <= yhi; ++yy) {
                const int* rp = T + bOff + (size_t)zz * ZS + (size_t)yy * DX;
                for (int xx = xlo; xx <= xhi; ++xx)
                    if (rp[xx] != tv) return r;
            }
    }
    return 21;
}

// ---------------- fused main kernel: direct loads, per-block partials -------
__global__ __launch_bounds__(BLOCK) void boundary_loss_kernel(
    const float* __restrict__ inp,   // (4,2,96,192,192) f32
    const int* __restrict__ tgt,     // (4,1,96,192,192) i32 in {0,1}
    float4* __restrict__ P)          // per-block (s1, s2, fg, 0)
{
    const int b = blockIdx.x / BLOCKS_PER_BATCH;
    const size_t bOff = (size_t)b * SVOL;
    const int gid = blockIdx.x * BLOCK + threadIdx.x;
    const size_t vox = (size_t)gid * VOX_PER_THREAD;
    const int rem = (int)(vox - bOff);          // < 3.54M, fits int32
    const int z = rem / ZS;
    const int ry = rem - z * ZS;
    const int y = ry / DX;
    const int x0 = ry - y * DX;                 // multiple of 8

    // x-OOB bit fixes: bit j of packed row p = target at x0-1+j, j in [0,9]
    uint32_t mxo = ~0u, mxa = 0u;
    if (x0 == 0)      { mxo &= ~1u;        mxa |= 1u; }
    if (x0 == DX - 8) { mxo &= ~(1u << 9); mxa |= (1u << 9); }
    const int ax = (x0 == 0) ? 0 : x0 - 4;            // aligned int4 covering x0-1
    const int dx8 = (x0 == DX - 8) ? DX - 1 : x0 + 8; // clamped x0+8

    uint32_t OR9 = 0u, AND9 = ~0u, pc = 0u;
    const int* Tb = tgt + bOff;
    #pragma unroll
    for (int dz = -1; dz <= 1; ++dz) {
        int zz = z + dz;
        if (zz < 0 || zz >= DZ) continue;
        #pragma unroll
        for (int dy = -1; dy <= 1; ++dy) {
            int yy = y + dy;
            if (yy < 0 || yy >= DY) continue;
            const int* rp = Tb + (size_t)zz * ZS + (size_t)yy * DX;
            int4 a = *(const int4*)(rp + ax);     // only .w (x0-1) used
            int4 q = *(const int4*)(rp + x0);     // x0..x0+3
            int4 c = *(const int4*)(rp + x0 + 4); // x0+4..x0+7
            int  dd = rp[dx8];                    // x0+8 (or masked)
            uint32_t p = (uint32_t)a.w
                | ((uint32_t)q.x << 1) | ((uint32_t)q.y << 2)
                | ((uint32_t)q.z << 3) | ((uint32_t)q.w << 4)
                | ((uint32_t)c.x << 5) | ((uint32_t)c.y << 6)
                | ((uint32_t)c.z << 7) | ((uint32_t)c.w << 8)
                | ((uint32_t)dd  << 9);
            if (dz == 0 && dy == 0) pc = p;
            uint32_t po = p & mxo;
            uint32_t pa = p | mxa;
            OR9  |= po | (po >> 1) | (po >> 2);   // 3-tap horizontal OR
            AND9 &= pa & (pa >> 1) & (pa >> 2);   // 3-tap horizontal AND
        }
    }
    const uint32_t diff8 = (OR9 ^ AND9) & 0xFFu; // bit i: voxel x0+i has opposite 26-neighbor
    const uint32_t tc8   = (pc >> 1) & 0xFFu;    // bit i: t at voxel x0+i

    // probs_fg = sigmoid(x1 - x0)
    const size_t sp = (size_t)z * ZS + (size_t)y * DX + x0;
    const float* i0 = inp + ((size_t)(2 * b)) * SVOL + sp;
    const float* i1 = i0 + SVOL;
    float4 A0 = *(const float4*)(i0), A1 = *(const float4*)(i0 + 4);
    float4 B0 = *(const float4*)(i1), B1 = *(const float4*)(i1 + 4);
    float c0[8] = {A0.x, A0.y, A0.z, A0.w, A1.x, A1.y, A1.z, A1.w};
    float c1[8] = {B0.x, B0.y, B0.z, B0.w, B1.x, B1.y, B1.z, B1.w};

    float s1 = 0.f, s2 = 0.f;
    #pragma unroll
    for (int i = 0; i < VOX_PER_THREAD; ++i) {
        float e   = __expf(c0[i] - c1[i]);
        float sig = __builtin_amdgcn_rcpf(1.0f + e);
        int ti = (int)((tc8 >> i) & 1u);
        float val = (float)ti;                   // D==1 closed form
        if (!((diff8 >> i) & 1u)) {              // astronomically rare exact path
            int D = far_dist(tgt, bOff, z, y, x0 + i, ti);
            int mm = min(D - 1, 20);
            val = ti ? (1.0f - (float)mm) : (float)mm;
        }
        s1 = fmaf(sig, val, s1);
        s2 += sig;
    }
    float s3 = (tc8 != 0u) ? 1.f : 0.f;          // foreground presence

    // wave reduce (64 lanes), then block reduce via LDS, single plain store
    #pragma unroll
    for (int off = 32; off > 0; off >>= 1) {
        s1 += __shfl_down(s1, off);
        s2 += __shfl_down(s2, off);
        s3 += __shfl_down(s3, off);
    }
    __shared__ float red1[BLOCK / 64], red2[BLOCK / 64], red3[BLOCK / 64];
    const int lane = threadIdx.x & 63, wid = threadIdx.x >> 6;
    if (lane == 0) { red1[wid] = s1; red2[wid] = s2; red3[wid] = s3; }
    __syncthreads();
    if (threadIdx.x == 0) {
        P[blockIdx.x] = make_float4(red1[0] + red1[1] + red1[2] + red1[3],
                                    red2[0] + red2[1] + red2[2] + red2[3],
                                    red3[0] + red3[1] + red3[2] + red3[3], 0.f);
    }
}

// ---------------- final reduction: 6912 partials -> scalar loss -------------
__global__ __launch_bounds__(1024) void reduce_kernel(
    const float4* __restrict__ P, float* __restrict__ out)
{
    const int tid = threadIdx.x;
    const int lane = tid & 63, wid = tid >> 6;
    __shared__ double L1[16], L2[16], L3[16];
    double tot = 0.0;

    for (int b = 0; b < BATCH; ++b) {
        double d1 = 0.0, d2 = 0.0, d3 = 0.0;
        for (int i = tid; i < BLOCKS_PER_BATCH; i += 1024) {
            float4 p = P[b * BLOCKS_PER_BATCH + i];
            d1 += p.x; d2 += p.y; d3 += p.z;
        }
        #pragma unroll
        for (int off = 32; off > 0; off >>= 1) {
            d1 += __shfl_down(d1, off);
            d2 += __shfl_down(d2, off);
            d3 += __shfl_down(d3, off);
        }
        if (lane == 0) { L1[wid] = d1; L2[wid] = d2; L3[wid] = d3; }
        __syncthreads();
        if (tid == 0) {
            double s1 = 0.0, s2 = 0.0, s3 = 0.0;
            #pragma unroll
            for (int w = 0; w < 16; ++w) { s1 += L1[w]; s2 += L2[w]; s3 += L3[w]; }
            tot += (s3 > 0.0) ? s1 : s2;   // no_fg batch: dist_map == 1 everywhere
        }
        __syncthreads();
    }
    if (tid == 0) out[0] = (float)(tot / NTOT);
}

extern "C" void kernel_launch(void* const* d_in, const int* in_sizes, int n_in,
                              void* d_out, int out_size, void* d_ws, size_t ws_size,
                              hipStream_t stream) {
    const float* inp = (const float*)d_in[0];
    const int*   tgt = (const int*)d_in[1];
    float* out = (float*)d_out;
    float4* P = (float4*)d_ws;                    // 6912 * 16 B partials

    hipLaunchKernelGGL(boundary_loss_kernel, dim3(GRID), dim3(BLOCK), 0, stream,
                       inp, tgt, P);
    hipLaunchKernelGGL(reduce_kernel, dim3(1), dim3(1024), 0, stream, P, out);
}

// Round 6
// 249.463 us; speedup vs baseline: 1.0034x; 1.0034x over previous
//
#include <hip/hip_runtime.h>
#include <hip/hip_bf16.h>

// Problem geometry (fixed by setup_inputs)
#define BATCH 4
#define DZ 96
#define DY 192
#define DX 192
#define ZS (DY * DX)            // 36864
#define SVOL ((size_t)DZ * ZS)  // 3538944 voxels per batch item
#define NTOT ((double)(4.0 * (double)SVOL))

// Tiling: block = z-tile(4) x y-tile(16) x full-x(192) = 12288 voxels
#define ZT 4
#define YT 16
#define NZT (DZ / ZT)           // 24
#define NYT (DY / YT)           // 12
#define BLOCKS_PER_BATCH (NZT * NYT)          // 288
#define GRID (BATCH * BLOCKS_PER_BATCH)       // 1152
#define BLOCK 256

#define NP (ZT + 2)             // staged z-planes (halo)
#define NR (YT + 2)             // staged y-rows (halo)
#define ROWW 8                  // u32 words per staged row (6 used + 2 zero pad)
#define LDSW (NP * NR * ROWW)   // 864 u32 = 3456 B

// Exact expanding-box search for voxels whose entire (in-bounds) 26-neighborhood
// matches their own class (expected ~0 such voxels on Bernoulli targets).
__device__ __noinline__ int far_dist(const int* __restrict__ T, size_t bOff,
                                     int z, int y, int x, int tv) {
    for (int r = 2; r <= 20; ++r) {
        int zlo = max(z - r, 0), zhi = min(z + r, DZ - 1);
        int ylo = max(y - r, 0), yhi = min(y + r, DY - 1);
        int xlo = max(x - r, 0), xhi = min(x + r, DX - 1);
        for (int zz = zlo; zz <= zhi; ++zz)
            for (int yy = ylo; yy <= yhi; ++yy) {
                const int* rp = T + bOff + (size_t)zz * ZS + (size_t)yy * DX;
                for (int xx = xlo; xx <= xhi; ++xx)
                    if (rp[xx] != tv) return r;
            }
    }
    return 21;
}

// ---------------- main fused kernel: LDS-staged target bits -----------------
__global__ __launch_bounds__(BLOCK, 4) void boundary_loss_kernel(
    const float* __restrict__ inp,   // (4,2,96,192,192) f32
    const int* __restrict__ tgt,     // (4,1,96,192,192) i32 in {0,1}
    float4* __restrict__ P)          // per-block (s1, s2, fg, 0)
{
    const int bi = blockIdx.x;
    const int b  = bi / BLOCKS_PER_BATCH;
    const int tr = bi - b * BLOCKS_PER_BATCH;
    const int zt = tr / NYT;
    const int yt = tr - zt * NYT;
    const int z0 = zt * ZT;
    const int y0 = yt * YT;
    const size_t bOff = (size_t)b * SVOL;
    const int* Tb = tgt + bOff;

    // ---- stage: pack (6 planes x 18 rows x 192 bits) of targets into LDS ----
    __shared__ uint32_t L[LDSW];
    for (int i = threadIdx.x; i < LDSW; i += BLOCK) L[i] = 0u;
    __syncthreads();
    // 6*18*48 = 5184 int4-load tasks; clamped z/y halo (duplicates are
    // idempotent under the OR/AND neighborhood reduction).
    for (int task = threadIdx.x; task < NP * NR * 48; task += BLOCK) {
        const int rid = task / 48;
        const int xq  = task - rid * 48;         // int4 index within row
        const int pz  = rid / NR;
        const int py  = rid - pz * NR;
        const int zz  = min(max(z0 - 1 + pz, 0), DZ - 1);
        const int yy  = min(max(y0 - 1 + py, 0), DY - 1);
        const int4 v = *(const int4*)(Tb + (size_t)zz * ZS + (size_t)yy * DX + xq * 4);
        const uint32_t nib = (uint32_t)(v.x & 1) | ((uint32_t)(v.y & 1) << 1)
                           | ((uint32_t)(v.z & 1) << 2) | ((uint32_t)(v.w & 1) << 3);
        atomicOr(&L[rid * ROWW + (xq >> 3)], nib << ((xq & 7) * 4));
    }
    __syncthreads();

    // ---- compute: thread = (x-segment s, y-row r); iterates 4 z-planes ------
    const int s  = threadIdx.x & 15;             // 16 segments of 12 voxels
    const int r  = threadIdx.x >> 4;             // 16 y-rows
    const int x0 = s * 12;
    const int y  = y0 + r;

    // 14-bit window: bit j = t[x0-1+j], j in [0,13]
    const int  q    = (x0 == 0) ? 0 : (x0 - 1);
    const int  wofs = q >> 5;
    const int  sh   = q & 31;
    const bool atL  = (s == 0);
    const uint32_t forceA = (s == 0 ? 1u : 0u) | (s == 15 ? (1u << 13) : 0u);

    auto rowwin = [&](int pz, int py) -> uint32_t {
        const uint32_t* Lp = &L[(pz * NR + py) * ROWW + wofs];
        const uint64_t v = (uint64_t)Lp[0] | ((uint64_t)Lp[1] << 32);
        return atL ? (uint32_t)((v << 1) & 0x3FFFu)
                   : (uint32_t)((v >> sh) & 0x3FFFu);
    };

    uint32_t PO[3], PA[3], TW[3];
    auto plane = [&](int pz, int slot) {
        uint32_t o = 0u, a = 0xFFFFFFFFu, tw = 0u;
        #pragma unroll
        for (int dy = 0; dy < 3; ++dy) {         // rows y-1,y,y+1 -> py=r+dy
            const uint32_t w  = rowwin(pz, r + dy);
            if (dy == 1) tw = w;
            const uint32_t wa = w | forceA;
            o |= (w | (w >> 1) | (w >> 2));
            a &= (wa & (wa >> 1) & (wa >> 2));
        }
        PO[slot] = o & 0xFFFu; PA[slot] = a & 0xFFFu; TW[slot] = tw;
    };

    plane(0, 0);
    plane(1, 1);

    float s1 = 0.f, s2 = 0.f;
    uint32_t fg = 0u;

    #pragma unroll
    for (int k = 0; k < ZT; ++k) {
        plane(k + 2, (k + 2) % 3);
        const int z = z0 + k;
        const uint32_t diff = (PO[0] | PO[1] | PO[2]) ^ (PA[0] & PA[1] & PA[2]);
        const uint32_t tc   = (TW[(k + 1) % 3] >> 1) & 0xFFFu;
        fg |= tc;

        const float* i0 = inp + ((size_t)(2 * b)) * SVOL
                        + (size_t)z * ZS + (size_t)y * DX + x0;
        const float* i1 = i0 + SVOL;
        float4 A0 = *(const float4*)(i0),     A1 = *(const float4*)(i0 + 4),
               A2 = *(const float4*)(i0 + 8);
        float4 B0 = *(const float4*)(i1),     B1 = *(const float4*)(i1 + 4),
               B2 = *(const float4*)(i1 + 8);
        float c0[12] = {A0.x,A0.y,A0.z,A0.w, A1.x,A1.y,A1.z,A1.w, A2.x,A2.y,A2.z,A2.w};
        float c1[12] = {B0.x,B0.y,B0.z,B0.w, B1.x,B1.y,B1.z,B1.w, B2.x,B2.y,B2.z,B2.w};

        #pragma unroll
        for (int i = 0; i < 12; ++i) {
            const float e   = __expf(c0[i] - c1[i]);
            const float sig = __builtin_amdgcn_rcpf(1.0f + e);
            const int ti = (int)((tc >> i) & 1u);
            float val = (float)ti;               // D==1 closed form
            if (!((diff >> i) & 1u)) {           // astronomically rare exact path
                const int D = far_dist(tgt, bOff, z, y, x0 + i, ti);
                const int mm = min(D - 1, 20);
                val = ti ? (1.0f - (float)mm) : (float)mm;
            }
            s1 = fmaf(sig, val, s1);
            s2 += sig;
        }
    }
    float s3 = fg ? 1.f : 0.f;

    // wave reduce (64 lanes), then block reduce via LDS, single plain store
    #pragma unroll
    for (int off = 32; off > 0; off >>= 1) {
        s1 += __shfl_down(s1, off);
        s2 += __shfl_down(s2, off);
        s3 += __shfl_down(s3, off);
    }
    __shared__ float red1[BLOCK / 64], red2[BLOCK / 64], red3[BLOCK / 64];
    const int lane = threadIdx.x & 63, wid = threadIdx.x >> 6;
    if (lane == 0) { red1[wid] = s1; red2[wid] = s2; red3[wid] = s3; }
    __syncthreads();
    if (threadIdx.x == 0) {
        P[blockIdx.x] = make_float4(red1[0] + red1[1] + red1[2] + red1[3],
                                    red2[0] + red2[1] + red2[2] + red2[3],
                                    red3[0] + red3[1] + red3[2] + red3[3], 0.f);
    }
}

// ---------------- final reduction: 1152 partials -> scalar loss -------------
__global__ __launch_bounds__(1024) void reduce_kernel(
    const float4* __restrict__ P, float* __restrict__ out)
{
    const int tid = threadIdx.x;
    const int lane = tid & 63, wid = tid >> 6;
    __shared__ double L1[16], L2[16], L3[16];
    double tot = 0.0;

    for (int b = 0; b < BATCH; ++b) {
        double d1 = 0.0, d2 = 0.0, d3 = 0.0;
        for (int i = tid; i < BLOCKS_PER_BATCH; i += 1024) {
            float4 p = P[b * BLOCKS_PER_BATCH + i];
            d1 += p.x; d2 += p.y; d3 += p.z;
        }
        #pragma unroll
        for (int off = 32; off > 0; off >>= 1) {
            d1 += __shfl_down(d1, off);
            d2 += __shfl_down(d2, off);
            d3 += __shfl_down(d3, off);
        }
        if (lane == 0) { L1[wid] = d1; L2[wid] = d2; L3[wid] = d3; }
        __syncthreads();
        if (tid == 0) {
            double t1 = 0.0, t2 = 0.0, t3 = 0.0;
            #pragma unroll
            for (int w = 0; w < 16; ++w) { t1 += L1[w]; t2 += L2[w]; t3 += L3[w]; }
            tot += (t3 > 0.0) ? t1 : t2;   // no_fg batch: dist_map == 1 everywhere
        }
        __syncthreads();
    }
    if (tid == 0) out[0] = (float)(tot / NTOT);
}

extern "C" void kernel_launch(void* const* d_in, const int* in_sizes, int n_in,
                              void* d_out, int out_size, void* d_ws, size_t ws_size,
                              hipStream_t stream) {
    const float* inp = (const float*)d_in[0];
    const int*   tgt = (const int*)d_in[1];
    float* out = (float*)d_out;
    float4* P = (float4*)d_ws;                   // 1152 * 16 B partials

    hipLaunchKernelGGL(boundary_loss_kernel, dim3(GRID), dim3(BLOCK), 0, stream,
                       inp, tgt, P);
    hipLaunchKernelGGL(reduce_kernel, dim3(1), dim3(1024), 0, stream, P, out);
}

// Round 7
// 239.078 us; speedup vs baseline: 1.0470x; 1.0434x over previous
//
#include <hip/hip_runtime.h>
#include <hip/hip_bf16.h>

// Problem geometry (fixed by setup_inputs)
#define BATCH 4
#define DZ 96
#define DY 192
#define DX 192
#define ZS (DY * DX)            // 36864
#define SVOL ((size_t)DZ * ZS)  // 3538944 voxels per batch item
#define NTOT ((double)(4.0 * (double)SVOL))
#define VOX_PER_THREAD 8
#define BLOCK 256
#define BLOCKS_PER_BATCH ((int)(SVOL / (VOX_PER_THREAD * BLOCK))) // 1728
#define GRID (BATCH * BLOCKS_PER_BATCH)                           // 6912

#define WORDS_TOTAL ((int)((BATCH * SVOL) / 64))   // 221184 u64 words
#define MAP_BYTES ((size_t)WORDS_TOTAL * 8)        // 1769472 B per bitmap
#define PART_BYTES ((size_t)GRID * 16)             // float4 per block
#define WS_NEED (PART_BYTES + 3 * MAP_BYTES)

// Exact expanding-box search for voxels whose entire (in-bounds) 26-neighborhood
// matches their own class (expected ~10 in the whole tensor, at faces/edges).
__device__ __noinline__ int far_dist(const int* __restrict__ T, size_t bOff,
                                     int z, int y, int x, int tv) {
    for (int r = 2; r <= 20; ++r) {
        int zlo = max(z - r, 0), zhi = min(z + r, DZ - 1);
        int ylo = max(y - r, 0), yhi = min(y + r, DY - 1);
        int xlo = max(x - r, 0), xhi = min(x + r, DX - 1);
        for (int zz = zlo; zz <= zhi; ++zz)
            for (int yy = ylo; yy <= yhi; ++yy) {
                const int* rp = T + bOff + (size_t)zz * ZS + (size_t)yy * DX;
                for (int xx = xlo; xx <= xhi; ++xx)
                    if (rp[xx] != tv) return r;
            }
    }
    return 21;
}

// ---------------- pack kernel: int32 targets -> 3 bitmaps (R3, proven) ------
__global__ __launch_bounds__(256) void pack_kernel(
    const int* __restrict__ tgt,
    unsigned long long* __restrict__ Tm,
    unsigned long long* __restrict__ Om,
    unsigned long long* __restrict__ Am)
{
    const int tid = blockIdx.x * 256 + threadIdx.x;
    const int t = tgt[tid];
    const unsigned long long b = __ballot(t != 0);
    const int w = tid >> 6;                       // u64 word index
    const int lane = threadIdx.x & 63;
    const int xw = (w % 3) * 64;                  // word position in its 192-row
    const size_t base = ((size_t)w) << 6;

    int ev = 0;                                   // edge voxel value (lanes 0,63)
    if (lane == 0 && xw != 0)    ev = tgt[base - 1];
    if (lane == 63 && xw != 128) ev = tgt[base + 64];
    const int eL0 = __shfl(ev, 0);
    const int eR0 = __shfl(ev, 63);

    const unsigned long long eLor  = (xw != 0   && eL0 != 0) ? 1ull : 0ull;
    const unsigned long long eRor  = (xw != 128 && eR0 != 0) ? (1ull << 63) : 0ull;
    const unsigned long long eLand = (xw == 0   || eL0 != 0) ? 1ull : 0ull;
    const unsigned long long eRand = (xw == 128 || eR0 != 0) ? (1ull << 63) : 0ull;

    const unsigned long long horOR  = b | (b << 1) | (b >> 1) | eLor | eRor;
    const unsigned long long horAND = b & ((b << 1) | eLand) & ((b >> 1) | eRand);

    if (lane == 0) { Tm[w] = b; Om[w] = horOR; Am[w] = horAND; }
}

// ---------------- main kernel: bitmap byte-loads, per-block partials --------
__global__ __launch_bounds__(BLOCK) void boundary_loss_kernel(
    const float* __restrict__ inp,
    const int* __restrict__ tgt,
    const unsigned long long* __restrict__ Om,
    const unsigned long long* __restrict__ Am,
    const unsigned long long* __restrict__ Tm,
    float4* __restrict__ P)          // per-block (s1, s2, fg, 0)
{
    const int b = blockIdx.x / BLOCKS_PER_BATCH;
    const size_t bOff = (size_t)b * SVOL;
    const int gid = blockIdx.x * BLOCK + threadIdx.x;
    const size_t vox = (size_t)gid * VOX_PER_THREAD;
    const int rem = (int)(vox - bOff);
    const int z = rem / ZS;
    const int ry = rem - z * ZS;
    const int y = ry / DX;
    const int x0 = ry - y * DX;

    const size_t rowC = (size_t)(b * DZ + z) * DY + y;   // global row index
    const int bx = x0 >> 3;
    const unsigned char* O8 = (const unsigned char*)Om;
    const unsigned char* A8 = (const unsigned char*)Am;
    const unsigned char* T8 = (const unsigned char*)Tm;

    const int dzo[3] = {(z > 0) ? -1 : 0, 0, (z < DZ - 1) ? 1 : 0};
    const int vzf[3] = {z > 0, 1, z < DZ - 1};
    const int dyo[3] = {(y > 0) ? -1 : 0, 0, (y < DY - 1) ? 1 : 0};
    const int vyf[3] = {y > 0, 1, y < DY - 1};

    unsigned int or9 = 0u, and9 = 0xFFu;
    #pragma unroll
    for (int iz = 0; iz < 3; ++iz) {
        #pragma unroll
        for (int iy = 0; iy < 3; ++iy) {
            const size_t ba = (rowC + (long)dzo[iz] * DY + dyo[iy]) * 24 + bx;
            const unsigned int o = O8[ba];
            const unsigned int a = A8[ba];
            const unsigned int m = (vzf[iz] & vyf[iy]) ? 0xFFu : 0u;
            or9  |= o & m;
            and9 &= a | ~m;
        }
    }
    and9 &= 0xFFu;
    const unsigned int diff8 = or9 ^ and9;       // bit i: voxel has opposite 26-neighbor
    const unsigned int tc8 = T8[rowC * 24 + bx]; // bit i: t at voxel x0+i

    // probs_fg = sigmoid(x1 - x0)
    const size_t sp = (size_t)z * ZS + (size_t)y * DX + x0;
    const float* i0 = inp + ((size_t)(2 * b)) * SVOL + sp;
    const float* i1 = i0 + SVOL;
    float4 A0 = *(const float4*)(i0), A1 = *(const float4*)(i0 + 4);
    float4 B0 = *(const float4*)(i1), B1 = *(const float4*)(i1 + 4);
    float c0[8] = {A0.x, A0.y, A0.z, A0.w, A1.x, A1.y, A1.z, A1.w};
    float c1[8] = {B0.x, B0.y, B0.z, B0.w, B1.x, B1.y, B1.z, B1.w};

    float s1 = 0.f, s2 = 0.f;
    #pragma unroll
    for (int i = 0; i < VOX_PER_THREAD; ++i) {
        float e   = __expf(c0[i] - c1[i]);
        float sig = __builtin_amdgcn_rcpf(1.0f + e);
        int ti = (int)((tc8 >> i) & 1u);
        float val = (float)ti;                   // D==1 closed form
        if (!((diff8 >> i) & 1u)) {              // astronomically rare exact path
            int D = far_dist(tgt, bOff, z, y, x0 + i, ti);
            int mm = min(D - 1, 20);
            val = ti ? (1.0f - (float)mm) : (float)mm;
        }
        s1 = fmaf(sig, val, s1);
        s2 += sig;
    }
    float s3 = (tc8 != 0u) ? 1.f : 0.f;          // foreground presence

    // wave reduce (64 lanes), then block reduce via LDS, single plain store
    #pragma unroll
    for (int off = 32; off > 0; off >>= 1) {
        s1 += __shfl_down(s1, off);
        s2 += __shfl_down(s2, off);
        s3 += __shfl_down(s3, off);
    }
    __shared__ float red1[BLOCK / 64], red2[BLOCK / 64], red3[BLOCK / 64];
    const int lane = threadIdx.x & 63, wid = threadIdx.x >> 6;
    if (lane == 0) { red1[wid] = s1; red2[wid] = s2; red3[wid] = s3; }
    __syncthreads();
    if (threadIdx.x == 0) {
        P[blockIdx.x] = make_float4(red1[0] + red1[1] + red1[2] + red1[3],
                                    red2[0] + red2[1] + red2[2] + red2[3],
                                    red3[0] + red3[1] + red3[2] + red3[3], 0.f);
    }
}

// ---------------- direct fallback (only if ws too small for bitmaps) --------
__global__ __launch_bounds__(BLOCK) void boundary_loss_fallback(
    const float* __restrict__ inp, const int* __restrict__ tgt,
    float4* __restrict__ P)
{
    const int b = blockIdx.x / BLOCKS_PER_BATCH;
    const size_t bOff = (size_t)b * SVOL;
    const int gid = blockIdx.x * BLOCK + threadIdx.x;
    const size_t vox = (size_t)gid * VOX_PER_THREAD;
    const int rem = (int)(vox - bOff);
    const int z = rem / ZS;
    const int ry = rem - z * ZS;
    const int y = ry / DX;
    const int x0 = ry - y * DX;

    uint32_t mxo = ~0u, mxa = 0u;
    if (x0 == 0)      { mxo &= ~1u;        mxa |= 1u; }
    if (x0 == DX - 8) { mxo &= ~(1u << 9); mxa |= (1u << 9); }
    const int ax = (x0 == 0) ? 0 : x0 - 4;
    const int dx8 = (x0 == DX - 8) ? DX - 1 : x0 + 8;

    uint32_t OR9 = 0u, AND9 = ~0u, pc = 0u;
    const int* Tb = tgt + bOff;
    #pragma unroll
    for (int dz = -1; dz <= 1; ++dz) {
        int zz = z + dz;
        if (zz < 0 || zz >= DZ) continue;
        #pragma unroll
        for (int dy = -1; dy <= 1; ++dy) {
            int yy = y + dy;
            if (yy < 0 || yy >= DY) continue;
            const int* rp = Tb + (size_t)zz * ZS + (size_t)yy * DX;
            int4 a = *(const int4*)(rp + ax);
            int4 q = *(const int4*)(rp + x0);
            int4 c = *(const int4*)(rp + x0 + 4);
            int  dd = rp[dx8];
            uint32_t p = (uint32_t)a.w
                | ((uint32_t)q.x << 1) | ((uint32_t)q.y << 2)
                | ((uint32_t)q.z << 3) | ((uint32_t)q.w << 4)
                | ((uint32_t)c.x << 5) | ((uint32_t)c.y << 6)
                | ((uint32_t)c.z << 7) | ((uint32_t)c.w << 8)
                | ((uint32_t)dd  << 9);
            if (dz == 0 && dy == 0) pc = p;
            uint32_t po = p & mxo;
            uint32_t pa = p | mxa;
            OR9  |= po | (po >> 1) | (po >> 2);
            AND9 &= pa & (pa >> 1) & (pa >> 2);
        }
    }
    const uint32_t diff8 = (OR9 ^ AND9) & 0xFFu;
    const uint32_t tc8   = (pc >> 1) & 0xFFu;

    const size_t sp = (size_t)z * ZS + (size_t)y * DX + x0;
    const float* i0 = inp + ((size_t)(2 * b)) * SVOL + sp;
    const float* i1 = i0 + SVOL;
    float4 A0 = *(const float4*)(i0), A1 = *(const float4*)(i0 + 4);
    float4 B0 = *(const float4*)(i1), B1 = *(const float4*)(i1 + 4);
    float c0[8] = {A0.x, A0.y, A0.z, A0.w, A1.x, A1.y, A1.z, A1.w};
    float c1[8] = {B0.x, B0.y, B0.z, B0.w, B1.x, B1.y, B1.z, B1.w};

    float s1 = 0.f, s2 = 0.f;
    #pragma unroll
    for (int i = 0; i < VOX_PER_THREAD; ++i) {
        float e   = __expf(c0[i] - c1[i]);
        float sig = __builtin_amdgcn_rcpf(1.0f + e);
        int ti = (int)((tc8 >> i) & 1u);
        float val = (float)ti;
        if (!((diff8 >> i) & 1u)) {
            int D = far_dist(tgt, bOff, z, y, x0 + i, ti);
            int mm = min(D - 1, 20);
            val = ti ? (1.0f - (float)mm) : (float)mm;
        }
        s1 = fmaf(sig, val, s1);
        s2 += sig;
    }
    float s3 = (tc8 != 0u) ? 1.f : 0.f;

    #pragma unroll
    for (int off = 32; off > 0; off >>= 1) {
        s1 += __shfl_down(s1, off);
        s2 += __shfl_down(s2, off);
        s3 += __shfl_down(s3, off);
    }
    __shared__ float red1[BLOCK / 64], red2[BLOCK / 64], red3[BLOCK / 64];
    const int lane = threadIdx.x & 63, wid = threadIdx.x >> 6;
    if (lane == 0) { red1[wid] = s1; red2[wid] = s2; red3[wid] = s3; }
    __syncthreads();
    if (threadIdx.x == 0) {
        P[blockIdx.x] = make_float4(red1[0] + red1[1] + red1[2] + red1[3],
                                    red2[0] + red2[1] + red2[2] + red2[3],
                                    red3[0] + red3[1] + red3[2] + red3[3], 0.f);
    }
}

// ---------------- final reduction: 6912 partials -> scalar loss -------------
__global__ __launch_bounds__(1024) void reduce_kernel(
    const float4* __restrict__ P, float* __restrict__ out)
{
    const int tid = threadIdx.x;
    const int lane = tid & 63, wid = tid >> 6;
    __shared__ double L1[16], L2[16], L3[16];
    double tot = 0.0;

    for (int b = 0; b < BATCH; ++b) {
        double d1 = 0.0, d2 = 0.0, d3 = 0.0;
        for (int i = tid; i < BLOCKS_PER_BATCH; i += 1024) {
            float4 p = P[b * BLOCKS_PER_BATCH + i];
            d1 += p.x; d2 += p.y; d3 += p.z;
        }
        #pragma unroll
        for (int off = 32; off > 0; off >>= 1) {
            d1 += __shfl_down(d1, off);
            d2 += __shfl_down(d2, off);
            d3 += __shfl_down(d3, off);
        }
        if (lane == 0) { L1[wid] = d1; L2[wid] = d2; L3[wid] = d3; }
        __syncthreads();
        if (tid == 0) {
            double t1 = 0.0, t2 = 0.0, t3 = 0.0;
            #pragma unroll
            for (int w = 0; w < 16; ++w) { t1 += L1[w]; t2 += L2[w]; t3 += L3[w]; }
            tot += (t3 > 0.0) ? t1 : t2;   // no_fg batch: dist_map == 1 everywhere
        }
        __syncthreads();
    }
    if (tid == 0) out[0] = (float)(tot / NTOT);
}

extern "C" void kernel_launch(void* const* d_in, const int* in_sizes, int n_in,
                              void* d_out, int out_size, void* d_ws, size_t ws_size,
                              hipStream_t stream) {
    const float* inp = (const float*)d_in[0];
    const int*   tgt = (const int*)d_in[1];
    float* out = (float*)d_out;
    float4* P = (float4*)d_ws;                    // 6912 * 16 B partials

    if (ws_size >= WS_NEED) {
        unsigned long long* Tm = (unsigned long long*)((char*)d_ws + PART_BYTES);
        unsigned long long* Om = Tm + WORDS_TOTAL;
        unsigned long long* Am = Om + WORDS_TOTAL;
        hipLaunchKernelGGL(pack_kernel, dim3((BATCH * (int)SVOL) / 256), dim3(256),
                           0, stream, tgt, Tm, Om, Am);
        hipLaunchKernelGGL(boundary_loss_kernel, dim3(GRID), dim3(BLOCK), 0, stream,
                           inp, tgt, Om, Am, Tm, P);
    } else {
        hipLaunchKernelGGL(boundary_loss_fallback, dim3(GRID), dim3(BLOCK), 0, stream,
                           inp, tgt, P);
    }
    hipLaunchKernelGGL(reduce_kernel, dim3(1), dim3(1024), 0, stream, P, out);
}